// Round 12
// baseline (51.423 us; speedup 1.0000x reference)
//
#include <hip/hip_runtime.h>

#define Bq 2
#define Nq 1024
#define Cq 128
#define Eq 64
#define Kq 20
#define TI 8
#define BN (Bq * Nq)
#define BNK (BN * Kq)
#define NEGF (-3.0e38f)

#define DPP_F(x, ctrl) __int_as_float(__builtin_amdgcn_update_dpp( \
    __float_as_int(x), __float_as_int(x), (ctrl), 0xf, 0xf, false))
#define DPP_I(x, ctrl) __builtin_amdgcn_update_dpp((x), (x), (ctrl), 0xf, 0xf, false)
#define RL_F(x, l) __int_as_float(__builtin_amdgcn_readlane(__float_as_int(x), (l)))
#define RL_I(x, l) __builtin_amdgcn_readlane((x), (l))
#define QP_XOR1 0xB1   // quad_perm [1,0,3,2]
#define QP_XOR2 0x4E   // quad_perm [2,3,0,1]
#define ROR4    0x124  // row_ror:4
#define ROR8    0x128  // row_ror:8

// ---------------- proj: x@Wl+bl -> xl ; x@Wr+br -> xrP (plane-major) + rdot ----------------
// grid = B*N, block = 128 (2 waves). Wave 0 -> Wl, wave 1 -> Wr. (unchanged)
__global__ __launch_bounds__(128) void proj_kernel(
    const float* __restrict__ x, const float* __restrict__ Wl,
    const float* __restrict__ bl, const float* __restrict__ Wr,
    const float* __restrict__ br, const float* __restrict__ att,
    float* __restrict__ xl, float* __restrict__ xrP, float* __restrict__ rdot) {
  const int row = blockIdx.x;
  const int t = threadIdx.x;
  const int e = t & 63;
  const bool left = (t < 64);
  __shared__ float xs[Cq];
  xs[t] = x[(size_t)row * Cq + t];
  __syncthreads();
  const float* __restrict__ W = left ? Wl : Wr;
  float acc = 0.f;
#pragma unroll 8
  for (int c = 0; c < Cq; ++c) acc = fmaf(xs[c], W[c * Eq + e], acc);
  acc += left ? bl[e] : br[e];
  if (left) {
    xl[(size_t)row * Eq + e] = acc;
  } else {
    // plane-major: xrP[ch=e>>2][row][c=e&3]
    xrP[((size_t)(e >> 2) * BN + row) * 4 + (e & 3)] = acc;
    float s = acc * att[e];                 // rdot[row] = sum_e xr[row][e]*att[e]
    s += DPP_F(s, QP_XOR1);
    s += DPP_F(s, QP_XOR2);
    s += DPP_F(s, ROR4);
    s += DPP_F(s, ROR8);
    const float sd = (RL_F(s, 0) + RL_F(s, 16)) + (RL_F(s, 32) + RL_F(s, 48));
    if (e == 0) rdot[row] = sd;
  }
}

// ---------------- attn: V_D core (8 rows x 2 j) + 2-ahead pipeline + top-K ----------------
// grid = BN/8 = 256 blocks, block = 512 (8 waves), VGPR capped 128 via launch_bounds.
// Phase 1: thread = 8 rows x (j = jt, jt+512); xl/att via wave-uniform s_loads.
// Phase 2: waves 0..7 own rows 0..7 (DPP-only top-K), no idle waves.
__global__ __launch_bounds__(512, 4) void attn_kernel(
    const float* __restrict__ xl, const float* __restrict__ xrP,
    const float* __restrict__ rdot, const float* __restrict__ att,
    float* __restrict__ out) {
  const int r0g  = blockIdx.x * TI;
  const int b    = r0g >> 10;
  const int tid  = threadIdx.x;
  const int lane = tid & 63;
  const int wave = tid >> 6;

  __shared__ float alpha[TI][Nq];   // 32 KB

  // ---- phase 1 ----
  {
    const int jt = tid;
    const float* __restrict__ xlw = xl + (size_t)r0g * Eq;  // block-uniform -> s_load

    const float rd0 = 1.5f * rdot[b * Nq + jt];
    const float rd1 = 1.5f * rdot[b * Nq + jt + 512];
    float acc[TI][2];
#pragma unroll
    for (int r = 0; r < TI; ++r) { acc[r][0] = rd0; acc[r][1] = rd1; }

    const float* __restrict__ vb = xrP + (size_t)(b * Nq + jt) * 4;
    const size_t plane = (size_t)BN * 4;   // floats per plane

    // 2-ahead software pipeline: planes ch and ch+1 in flight (4 outstanding loads)
    float4 va[2], vc[2];
    va[0] = *(const float4*)(vb);
    vc[0] = *(const float4*)(vb + 512 * 4);
    va[1] = *(const float4*)(vb + plane);
    vc[1] = *(const float4*)(vb + plane + 512 * 4);

#pragma unroll
    for (int ch = 0; ch < 16; ++ch) {
      const float4 v0 = va[ch & 1];        // static parity index (full unroll)
      const float4 v1 = vc[ch & 1];
      if (ch < 14) {                       // issue ch+2 before computing ch
        va[ch & 1] = *(const float4*)(vb + (ch + 2) * plane);
        vc[ch & 1] = *(const float4*)(vb + (ch + 2) * plane + 512 * 4);
      }
      const float4 at = *(const float4*)(att + ch * 4);   // uniform -> s_load
      const float* v0p = (const float*)&v0;
      const float* v1p = (const float*)&v1;
      const float* atp = (const float*)&at;
#pragma unroll
      for (int dd = 0; dd < 4; ++dd) {
        const float a = atp[dd];
        const float x0 = v0p[dd], x1 = v1p[dd];
#pragma unroll
        for (int r = 0; r < TI; ++r) {
          const float xld = xlw[r * Eq + ch * 4 + dd];    // uniform -> s_load
          acc[r][0] = fmaf(fabsf(xld + x0), a, acc[r][0]);
          acc[r][1] = fmaf(fabsf(xld + x1), a, acc[r][1]);
        }
      }
    }
#pragma unroll
    for (int r = 0; r < TI; ++r) {
      alpha[r][jt]       = acc[r][0];
      alpha[r][jt + 512] = acc[r][1];
    }
  }
  __syncthreads();

  // ---- phase 2: wave w = top-K of row w, DPP-only reduces ----
  {
    float vals[16];
#pragma unroll
    for (int s = 0; s < 16; ++s) vals[s] = alpha[wave][lane + 64 * s];

    float lv = vals[0];
    int   pk = lane;                      // pk = (s<<6)|lane == j
#pragma unroll
    for (int s = 1; s < 16; ++s)
      if (vals[s] > lv) { lv = vals[s]; pk = (s << 6) | lane; }

    float m0 = 0.f, ssum = 0.f, myv = 0.f;
    int myi = 0;
#pragma unroll 1
    for (int round = 0; round < Kq; ++round) {
      float m = lv;
      m = fmaxf(m, DPP_F(m, QP_XOR1));
      m = fmaxf(m, DPP_F(m, QP_XOR2));
      m = fmaxf(m, DPP_F(m, ROR4));
      m = fmaxf(m, DPP_F(m, ROR8));
      const float bv = fmaxf(fmaxf(RL_F(m, 0), RL_F(m, 16)),
                             fmaxf(RL_F(m, 32), RL_F(m, 48)));
      int key = (lv == bv) ? pk : 0x7FFFFFFF;   // min-j tie-break (lax.top_k)
      key = min(key, DPP_I(key, QP_XOR1));
      key = min(key, DPP_I(key, QP_XOR2));
      key = min(key, DPP_I(key, ROR4));
      key = min(key, DPP_I(key, ROR8));
      const int jsel = min(min(RL_I(key, 0), RL_I(key, 16)),
                           min(RL_I(key, 32), RL_I(key, 48)));
      if (round == 0) m0 = bv;
      ssum += __expf(0.4f * (bv - m0));   // undo the /0.4 scaling here
      if (lane == round) { myv = bv; myi = jsel; }
      if (lane == (jsel & 63)) {          // owner knockout + rescan
        const int sk = jsel >> 6;
#pragma unroll
        for (int s = 0; s < 16; ++s)
          if (s == sk) vals[s] = NEGF;
        lv = vals[0]; pk = lane;
#pragma unroll
        for (int s = 1; s < 16; ++s)
          if (vals[s] > lv) { lv = vals[s]; pk = (s << 6) | lane; }
      }
    }

    if (lane < Kq) {
      const int gi = r0g + wave;
      const float p = __expf(0.4f * (myv - m0)) / ssum;
      const int base = gi * Kq + lane;
      out[base]            = (float)gi;              // index_i
      out[BNK + base]      = (float)(b * Nq + myi);  // index_j
      out[2 * BNK + base]  = p;                      // attention
    }
  }
}

extern "C" void kernel_launch(void* const* d_in, const int* in_sizes, int n_in,
                              void* d_out, int out_size, void* d_ws, size_t ws_size,
                              hipStream_t stream) {
  const float* x   = (const float*)d_in[0];
  const float* Wl  = (const float*)d_in[1];
  const float* bl  = (const float*)d_in[2];
  const float* Wr  = (const float*)d_in[3];
  const float* br  = (const float*)d_in[4];
  const float* att = (const float*)d_in[5];
  float* out = (float*)d_out;

  float* xl   = (float*)d_ws;                    // [B*N, E]
  float* xrP  = xl + (size_t)BN * Eq;            // [16][B*N][4] plane-major
  float* rdot = xrP + (size_t)16 * BN * 4;       // [B*N]

  proj_kernel<<<BN, 128, 0, stream>>>(x, Wl, bl, Wr, br, att, xl, xrP, rdot);
  attn_kernel<<<BN / TI, 512, 0, stream>>>(xl, xrP, rdot, att, out);
}

// Round 13
// 42.146 us; speedup vs baseline: 1.2201x; 1.2201x over previous
//
#include <hip/hip_runtime.h>

#define Bq 2
#define Nq 1024
#define Cq 128
#define Eq 64
#define Kq 20
#define TI 4
#define BN (Bq * Nq)
#define BNK (BN * Kq)
#define NEGF (-3.0e38f)

#define DPP_F(x, ctrl) __int_as_float(__builtin_amdgcn_update_dpp( \
    __float_as_int(x), __float_as_int(x), (ctrl), 0xf, 0xf, false))
#define DPP_I(x, ctrl) __builtin_amdgcn_update_dpp((x), (x), (ctrl), 0xf, 0xf, false)
#define RL_F(x, l) __int_as_float(__builtin_amdgcn_readlane(__float_as_int(x), (l)))
#define RL_I(x, l) __builtin_amdgcn_readlane((x), (l))
#define QP_XOR1 0xB1   // quad_perm [1,0,3,2]
#define QP_XOR2 0x4E   // quad_perm [2,3,0,1]
#define ROR4    0x124  // row_ror:4
#define ROR8    0x128  // row_ror:8

// ---------------- proj: x@Wl+bl -> xl ; x@Wr+br -> xrP (plane-major) + rdot ----------------
// grid = B*N, block = 128 (2 waves). Wave 0 -> Wl, wave 1 -> Wr. (unchanged, ~3us)
__global__ __launch_bounds__(128) void proj_kernel(
    const float* __restrict__ x, const float* __restrict__ Wl,
    const float* __restrict__ bl, const float* __restrict__ Wr,
    const float* __restrict__ br, const float* __restrict__ att,
    float* __restrict__ xl, float* __restrict__ xrP, float* __restrict__ rdot) {
  const int row = blockIdx.x;
  const int t = threadIdx.x;
  const int e = t & 63;
  const bool left = (t < 64);
  __shared__ float xs[Cq];
  xs[t] = x[(size_t)row * Cq + t];
  __syncthreads();
  const float* __restrict__ W = left ? Wl : Wr;
  float acc = 0.f;
#pragma unroll 8
  for (int c = 0; c < Cq; ++c) acc = fmaf(xs[c], W[c * Eq + e], acc);
  acc += left ? bl[e] : br[e];
  if (left) {
    xl[(size_t)row * Eq + e] = acc;
  } else {
    // plane-major: xrP[ch=e>>2][row][c=e&3]
    xrP[((size_t)(e >> 2) * BN + row) * 4 + (e & 3)] = acc;
    float s = acc * att[e];                 // rdot[row] = sum_e xr[row][e]*att[e]
    s += DPP_F(s, QP_XOR1);
    s += DPP_F(s, QP_XOR2);
    s += DPP_F(s, ROR4);
    s += DPP_F(s, ROR8);
    const float sd = (RL_F(s, 0) + RL_F(s, 16)) + (RL_F(s, 32) + RL_F(s, 48));
    if (e == 0) rdot[row] = sd;
  }
}

// ---------------- attn: R11-exact + L2 prefetch burst ----------------
// grid = BN/4 = 512 blocks, block = 512 (8 waves), __launch_bounds__(512) (NO min-waves:
// R12 showed (512,4) -> 28 VGPR -> scratch catastrophe).
// NEW: dependency-free prefetch of the block's full 256KB xrP batch slice (8 lines/thread,
// 64B stride, all misses in flight) pulls LLC-resident data into the local XCD L2 at max
// parallelism BEFORE the latency-sensitive 16-stage pipelined sweep.
__global__ __launch_bounds__(512) void attn_kernel(
    const float* __restrict__ xl, const float* __restrict__ xrP,
    const float* __restrict__ rdot, const float* __restrict__ att,
    float* __restrict__ out) {
  const int r0g  = blockIdx.x * TI;
  const int b    = r0g >> 10;
  const int tid  = threadIdx.x;
  const int lane = tid & 63;
  const int wave = tid >> 6;

  __shared__ float alpha[TI][Nq];   // 16 KB

  // ---- L2 prefetch burst: touch all 4096 64B lines of this batch's xrP slice ----
  // plane p = tid>>5 (16 planes x 32 threads); within plane: 8 lines at 64B stride.
  float pf;
  {
    const int p   = tid >> 5;
    const int sub = tid & 31;
    const float* __restrict__ pb =
        xrP + (size_t)p * BN * 4 + (size_t)b * Nq * 4 + (size_t)sub * 128;
    float s0 = 0.f;
#pragma unroll
    for (int l = 0; l < 8; ++l) s0 += pb[l * 16];   // 16 floats = 64B stride
    pf = s0;
  }

  // ---- phase 1: R11-exact V_C core (4 rows x 2 j, 1-ahead pipeline) ----
  {
    const int jt = tid;
    const float* __restrict__ xlw = xl + (size_t)r0g * Eq;  // block-uniform -> s_load

    // fold prefetch sum in as an exact no-op (finite data; not constant-foldable)
    const float rd0 = fmaf(pf, 0.0f, 1.5f * rdot[b * Nq + jt]);
    const float rd1 = 1.5f * rdot[b * Nq + jt + 512];
    float acc[TI][2];
#pragma unroll
    for (int r = 0; r < TI; ++r) { acc[r][0] = rd0; acc[r][1] = rd1; }

    const float* __restrict__ vb = xrP + (size_t)(b * Nq + jt) * 4;
    // 1-ahead software pipeline (prefetch ch=0)
    float4 nv0 = *(const float4*)(vb);
    float4 nv1 = *(const float4*)(vb + 512 * 4);
    float4 na0 = *(const float4*)(xlw);
    float4 na1 = *(const float4*)(xlw + Eq);
    float4 na2 = *(const float4*)(xlw + 2 * Eq);
    float4 na3 = *(const float4*)(xlw + 3 * Eq);
    float4 nat = *(const float4*)(att);

#pragma unroll
    for (int ch = 0; ch < 16; ++ch) {
      const float4 v0 = nv0, v1 = nv1;
      const float4 a0 = na0, a1 = na1, a2 = na2, a3 = na3, at = nat;
      if (ch < 15) {                      // issue ch+1 loads before computing ch
        vb += BN * 4;                     // next plane
        nv0 = *(const float4*)(vb);
        nv1 = *(const float4*)(vb + 512 * 4);
        na0 = *(const float4*)(xlw + (ch + 1) * 4);
        na1 = *(const float4*)(xlw + Eq + (ch + 1) * 4);
        na2 = *(const float4*)(xlw + 2 * Eq + (ch + 1) * 4);
        na3 = *(const float4*)(xlw + 3 * Eq + (ch + 1) * 4);
        nat = *(const float4*)(att + (ch + 1) * 4);
      }
      const float* v0p = (const float*)&v0;
      const float* v1p = (const float*)&v1;
      const float* a0p = (const float*)&a0;
      const float* a1p = (const float*)&a1;
      const float* a2p = (const float*)&a2;
      const float* a3p = (const float*)&a3;
      const float* atp = (const float*)&at;
#pragma unroll
      for (int dd = 0; dd < 4; ++dd) {
        const float a = atp[dd];
        const float x0 = v0p[dd], x1 = v1p[dd];
        acc[0][0] = fmaf(fabsf(a0p[dd] + x0), a, acc[0][0]);
        acc[0][1] = fmaf(fabsf(a0p[dd] + x1), a, acc[0][1]);
        acc[1][0] = fmaf(fabsf(a1p[dd] + x0), a, acc[1][0]);
        acc[1][1] = fmaf(fabsf(a1p[dd] + x1), a, acc[1][1]);
        acc[2][0] = fmaf(fabsf(a2p[dd] + x0), a, acc[2][0]);
        acc[2][1] = fmaf(fabsf(a2p[dd] + x1), a, acc[2][1]);
        acc[3][0] = fmaf(fabsf(a3p[dd] + x0), a, acc[3][0]);
        acc[3][1] = fmaf(fabsf(a3p[dd] + x1), a, acc[3][1]);
      }
    }
#pragma unroll
    for (int r = 0; r < TI; ++r) {
      alpha[r][jt]       = acc[r][0];
      alpha[r][jt + 512] = acc[r][1];
    }
  }
  asm volatile("" :: "v"(pf));   // keep prefetch loads live (rule #17)
  __syncthreads();

  // ---- phase 2: waves 0..3 = top-K of row `wave`, DPP-only reduces ----
  if (wave < TI) {
    float vals[16];
#pragma unroll
    for (int s = 0; s < 16; ++s) vals[s] = alpha[wave][lane + 64 * s];

    float lv = vals[0];
    int   pk = lane;                      // pk = (s<<6)|lane == j
#pragma unroll
    for (int s = 1; s < 16; ++s)
      if (vals[s] > lv) { lv = vals[s]; pk = (s << 6) | lane; }

    float m0 = 0.f, ssum = 0.f, myv = 0.f;
    int myi = 0;
#pragma unroll 1
    for (int round = 0; round < Kq; ++round) {
      float m = lv;
      m = fmaxf(m, DPP_F(m, QP_XOR1));
      m = fmaxf(m, DPP_F(m, QP_XOR2));
      m = fmaxf(m, DPP_F(m, ROR4));
      m = fmaxf(m, DPP_F(m, ROR8));
      const float bv = fmaxf(fmaxf(RL_F(m, 0), RL_F(m, 16)),
                             fmaxf(RL_F(m, 32), RL_F(m, 48)));
      int key = (lv == bv) ? pk : 0x7FFFFFFF;   // min-j tie-break (lax.top_k)
      key = min(key, DPP_I(key, QP_XOR1));
      key = min(key, DPP_I(key, QP_XOR2));
      key = min(key, DPP_I(key, ROR4));
      key = min(key, DPP_I(key, ROR8));
      const int jsel = min(min(RL_I(key, 0), RL_I(key, 16)),
                           min(RL_I(key, 32), RL_I(key, 48)));
      if (round == 0) m0 = bv;
      ssum += __expf(0.4f * (bv - m0));   // undo the /0.4 scaling here
      if (lane == round) { myv = bv; myi = jsel; }
      if (lane == (jsel & 63)) {          // owner knockout + rescan
        const int sk = jsel >> 6;
#pragma unroll
        for (int s = 0; s < 16; ++s)
          if (s == sk) vals[s] = NEGF;
        lv = vals[0]; pk = lane;
#pragma unroll
        for (int s = 1; s < 16; ++s)
          if (vals[s] > lv) { lv = vals[s]; pk = (s << 6) | lane; }
      }
    }

    if (lane < Kq) {
      const int gi = r0g + wave;
      const float p = __expf(0.4f * (myv - m0)) / ssum;
      const int base = gi * Kq + lane;
      out[base]            = (float)gi;              // index_i
      out[BNK + base]      = (float)(b * Nq + myi);  // index_j
      out[2 * BNK + base]  = p;                      // attention
    }
  }
}

extern "C" void kernel_launch(void* const* d_in, const int* in_sizes, int n_in,
                              void* d_out, int out_size, void* d_ws, size_t ws_size,
                              hipStream_t stream) {
  const float* x   = (const float*)d_in[0];
  const float* Wl  = (const float*)d_in[1];
  const float* bl  = (const float*)d_in[2];
  const float* Wr  = (const float*)d_in[3];
  const float* br  = (const float*)d_in[4];
  const float* att = (const float*)d_in[5];
  float* out = (float*)d_out;

  float* xl   = (float*)d_ws;                    // [B*N, E]
  float* xrP  = xl + (size_t)BN * Eq;            // [16][B*N][4] plane-major
  float* rdot = xrP + (size_t)16 * BN * 4;       // [B*N]

  proj_kernel<<<BN, 128, 0, stream>>>(x, Wl, bl, Wr, br, att, xl, xrP, rdot);
  attn_kernel<<<BN / TI, 512, 0, stream>>>(xl, xrP, rdot, att, out);
}

// Round 14
// 39.094 us; speedup vs baseline: 1.3154x; 1.0781x over previous
//
#include <hip/hip_runtime.h>

#define Bq 2
#define Nq 1024
#define Cq 128
#define Eq 64
#define Kq 20
#define TI 4
#define BN (Bq * Nq)
#define BNK (BN * Kq)
#define NEGF (-3.0e38f)

#define DPP_F(x, ctrl) __int_as_float(__builtin_amdgcn_update_dpp( \
    __float_as_int(x), __float_as_int(x), (ctrl), 0xf, 0xf, false))
#define DPP_I(x, ctrl) __builtin_amdgcn_update_dpp((x), (x), (ctrl), 0xf, 0xf, false)
#define RL_F(x, l) __int_as_float(__builtin_amdgcn_readlane(__float_as_int(x), (l)))
#define RL_I(x, l) __builtin_amdgcn_readlane((x), (l))
#define QP_XOR1 0xB1   // quad_perm [1,0,3,2]
#define QP_XOR2 0x4E   // quad_perm [2,3,0,1]
#define ROR4    0x124  // row_ror:4
#define ROR8    0x128  // row_ror:8

// ---------------- proj: x@Wl+bl -> xl ; x@Wr+br -> xrP (plane-major) + rdot ----------------
// grid = B*N, block = 128 (2 waves). Wave 0 -> Wl, wave 1 -> Wr. (R11-exact)
__global__ __launch_bounds__(128) void proj_kernel(
    const float* __restrict__ x, const float* __restrict__ Wl,
    const float* __restrict__ bl, const float* __restrict__ Wr,
    const float* __restrict__ br, const float* __restrict__ att,
    float* __restrict__ xl, float* __restrict__ xrP, float* __restrict__ rdot) {
  const int row = blockIdx.x;
  const int t = threadIdx.x;
  const int e = t & 63;
  const bool left = (t < 64);
  __shared__ float xs[Cq];
  xs[t] = x[(size_t)row * Cq + t];
  __syncthreads();
  const float* __restrict__ W = left ? Wl : Wr;
  float acc = 0.f;
#pragma unroll 8
  for (int c = 0; c < Cq; ++c) acc = fmaf(xs[c], W[c * Eq + e], acc);
  acc += left ? bl[e] : br[e];
  if (left) {
    xl[(size_t)row * Eq + e] = acc;
  } else {
    // plane-major: xrP[ch=e>>2][row][c=e&3]
    xrP[((size_t)(e >> 2) * BN + row) * 4 + (e & 3)] = acc;
    float s = acc * att[e];                 // rdot[row] = sum_e xr[row][e]*att[e]
    s += DPP_F(s, QP_XOR1);
    s += DPP_F(s, QP_XOR2);
    s += DPP_F(s, ROR4);
    s += DPP_F(s, ROR8);
    const float sd = (RL_F(s, 0) + RL_F(s, 16)) + (RL_F(s, 32) + RL_F(s, 48));
    if (e == 0) rdot[row] = sd;
  }
}

// ---------------- attn: plane-skewed sweep + 3-ahead pipeline + top-K ----------------
// grid = BN/4 = 512 blocks, block = 512 (8 waves), plain __launch_bounds__(512).
// Anti-hotspot: block k starts its plane sweep at plane (k & 15); combined with the
// rotated 3-deep prefetch this spreads the post-invalidate L2 fill across all lines.
__global__ __launch_bounds__(512) void attn_kernel(
    const float* __restrict__ xl, const float* __restrict__ xrP,
    const float* __restrict__ rdot, const float* __restrict__ att,
    float* __restrict__ out) {
  const int r0g  = blockIdx.x * TI;
  const int b    = r0g >> 10;
  const int tid  = threadIdx.x;
  const int lane = tid & 63;
  const int wave = tid >> 6;

  __shared__ float alpha[TI][Nq];   // 16 KB

  // ---- phase 1: skewed-start, 3-ahead pipelined sweep ----
  {
    const int jt = tid;
    const int start = blockIdx.x & 15;                      // per-block plane skew
    const float* __restrict__ xlw = xl + (size_t)r0g * Eq;  // block-uniform -> s_load
    const size_t rowoff = ((size_t)b * Nq + jt) * 4;

    const float rd0 = 1.5f * rdot[b * Nq + jt];
    const float rd1 = 1.5f * rdot[b * Nq + jt + 512];
    float acc[TI][2];
#pragma unroll
    for (int r = 0; r < TI; ++r) { acc[r][0] = rd0; acc[r][1] = rd1; }

    // rotated 3-deep prefetch buffers (static indices under full unroll)
    float4 v0b[3], v1b[3];
#pragma unroll
    for (int k = 0; k < 3; ++k) {
      const int p = (start + k) & 15;
      const float* __restrict__ pa = xrP + (size_t)p * BN * 4 + rowoff;
      v0b[k] = *(const float4*)(pa);
      v1b[k] = *(const float4*)(pa + 512 * 4);
    }

#pragma unroll
    for (int i = 0; i < 16; ++i) {
      const int p = (start + i) & 15;
      const float4 v0 = v0b[i % 3];
      const float4 v1 = v1b[i % 3];
      if (i < 13) {                        // issue plane i+3 before computing plane i
        const int pn = (start + i + 3) & 15;
        const float* __restrict__ pa = xrP + (size_t)pn * BN * 4 + rowoff;
        v0b[i % 3] = *(const float4*)(pa);
        v1b[i % 3] = *(const float4*)(pa + 512 * 4);
      }
      const float4 at = *(const float4*)(att + p * 4);          // uniform -> s_load
      const float4 a0 = *(const float4*)(xlw + p * 4);          // uniform -> s_load
      const float4 a1 = *(const float4*)(xlw + Eq + p * 4);
      const float4 a2 = *(const float4*)(xlw + 2 * Eq + p * 4);
      const float4 a3 = *(const float4*)(xlw + 3 * Eq + p * 4);
      const float* v0p = (const float*)&v0;
      const float* v1p = (const float*)&v1;
      const float* a0p = (const float*)&a0;
      const float* a1p = (const float*)&a1;
      const float* a2p = (const float*)&a2;
      const float* a3p = (const float*)&a3;
      const float* atp = (const float*)&at;
#pragma unroll
      for (int dd = 0; dd < 4; ++dd) {
        const float a = atp[dd];
        const float x0 = v0p[dd], x1 = v1p[dd];
        acc[0][0] = fmaf(fabsf(a0p[dd] + x0), a, acc[0][0]);
        acc[0][1] = fmaf(fabsf(a0p[dd] + x1), a, acc[0][1]);
        acc[1][0] = fmaf(fabsf(a1p[dd] + x0), a, acc[1][0]);
        acc[1][1] = fmaf(fabsf(a1p[dd] + x1), a, acc[1][1]);
        acc[2][0] = fmaf(fabsf(a2p[dd] + x0), a, acc[2][0]);
        acc[2][1] = fmaf(fabsf(a2p[dd] + x1), a, acc[2][1]);
        acc[3][0] = fmaf(fabsf(a3p[dd] + x0), a, acc[3][0]);
        acc[3][1] = fmaf(fabsf(a3p[dd] + x1), a, acc[3][1]);
      }
    }
#pragma unroll
    for (int r = 0; r < TI; ++r) {
      alpha[r][jt]       = acc[r][0];
      alpha[r][jt + 512] = acc[r][1];
    }
  }
  __syncthreads();

  // ---- phase 2: waves 0..3 = top-K of row `wave`, DPP-only reduces ----
  if (wave < TI) {
    float vals[16];
#pragma unroll
    for (int s = 0; s < 16; ++s) vals[s] = alpha[wave][lane + 64 * s];

    float lv = vals[0];
    int   pk = lane;                      // pk = (s<<6)|lane == j
#pragma unroll
    for (int s = 1; s < 16; ++s)
      if (vals[s] > lv) { lv = vals[s]; pk = (s << 6) | lane; }

    float m0 = 0.f, ssum = 0.f, myv = 0.f;
    int myi = 0;
#pragma unroll 1
    for (int round = 0; round < Kq; ++round) {
      float m = lv;
      m = fmaxf(m, DPP_F(m, QP_XOR1));
      m = fmaxf(m, DPP_F(m, QP_XOR2));
      m = fmaxf(m, DPP_F(m, ROR4));
      m = fmaxf(m, DPP_F(m, ROR8));
      const float bv = fmaxf(fmaxf(RL_F(m, 0), RL_F(m, 16)),
                             fmaxf(RL_F(m, 32), RL_F(m, 48)));
      int key = (lv == bv) ? pk : 0x7FFFFFFF;   // min-j tie-break (lax.top_k)
      key = min(key, DPP_I(key, QP_XOR1));
      key = min(key, DPP_I(key, QP_XOR2));
      key = min(key, DPP_I(key, ROR4));
      key = min(key, DPP_I(key, ROR8));
      const int jsel = min(min(RL_I(key, 0), RL_I(key, 16)),
                           min(RL_I(key, 32), RL_I(key, 48)));
      if (round == 0) m0 = bv;
      ssum += __expf(0.4f * (bv - m0));   // undo the /0.4 scaling here
      if (lane == round) { myv = bv; myi = jsel; }
      if (lane == (jsel & 63)) {          // owner knockout + rescan
        const int sk = jsel >> 6;
#pragma unroll
        for (int s = 0; s < 16; ++s)
          if (s == sk) vals[s] = NEGF;
        lv = vals[0]; pk = lane;
#pragma unroll
        for (int s = 1; s < 16; ++s)
          if (vals[s] > lv) { lv = vals[s]; pk = (s << 6) | lane; }
      }
    }

    if (lane < Kq) {
      const int gi = r0g + wave;
      const float p = __expf(0.4f * (myv - m0)) / ssum;
      const int base = gi * Kq + lane;
      out[base]            = (float)gi;              // index_i
      out[BNK + base]      = (float)(b * Nq + myi);  // index_j
      out[2 * BNK + base]  = p;                      // attention
    }
  }
}

extern "C" void kernel_launch(void* const* d_in, const int* in_sizes, int n_in,
                              void* d_out, int out_size, void* d_ws, size_t ws_size,
                              hipStream_t stream) {
  const float* x   = (const float*)d_in[0];
  const float* Wl  = (const float*)d_in[1];
  const float* bl  = (const float*)d_in[2];
  const float* Wr  = (const float*)d_in[3];
  const float* br  = (const float*)d_in[4];
  const float* att = (const float*)d_in[5];
  float* out = (float*)d_out;

  float* xl   = (float*)d_ws;                    // [B*N, E]
  float* xrP  = xl + (size_t)BN * Eq;            // [16][B*N][4] plane-major
  float* rdot = xrP + (size_t)16 * BN * 4;       // [B*N]

  proj_kernel<<<BN, 128, 0, stream>>>(x, Wl, bl, Wr, br, att, xl, xrP, rdot);
  attn_kernel<<<BN / TI, 512, 0, stream>>>(xl, xrP, rdot, att, out);
}

// Round 15
// 38.877 us; speedup vs baseline: 1.3227x; 1.0056x over previous
//
#include <hip/hip_runtime.h>

#define Bq 2
#define Nq 1024
#define Cq 128
#define Eq 64
#define Kq 20
#define TI 4
#define BN (Bq * Nq)
#define BNK (BN * Kq)
#define NEGF (-3.0e38f)

#define DPP_F(x, ctrl) __int_as_float(__builtin_amdgcn_update_dpp( \
    __float_as_int(x), __float_as_int(x), (ctrl), 0xf, 0xf, false))
#define DPP_I(x, ctrl) __builtin_amdgcn_update_dpp((x), (x), (ctrl), 0xf, 0xf, false)
#define RL_F(x, l) __int_as_float(__builtin_amdgcn_readlane(__float_as_int(x), (l)))
#define RL_I(x, l) __builtin_amdgcn_readlane((x), (l))
#define QP_XOR1 0xB1   // quad_perm [1,0,3,2]
#define QP_XOR2 0x4E   // quad_perm [2,3,0,1]
#define ROR4    0x124  // row_ror:4
#define ROR8    0x128  // row_ror:8

// ---------------- proj: identical to R11 EXCEPT all global outputs use ----------------
// non-temporal stores (global_store ... nt): results land CLEAN in LLC/HBM instead of
// dirty+scattered across 8 XCD L2s (each xrP line is written by 16 different blocks!).
// Theory: attn's invariant ~30us cold pass is dirty-line coherence sourcing, not miss
// latency (R13: independent-miss prefetch burst was null).
__global__ __launch_bounds__(128) void proj_kernel(
    const float* __restrict__ x, const float* __restrict__ Wl,
    const float* __restrict__ bl, const float* __restrict__ Wr,
    const float* __restrict__ br, const float* __restrict__ att,
    float* __restrict__ xl, float* __restrict__ xrP, float* __restrict__ rdot) {
  const int row = blockIdx.x;
  const int t = threadIdx.x;
  const int e = t & 63;
  const bool left = (t < 64);
  __shared__ float xs[Cq];
  xs[t] = x[(size_t)row * Cq + t];
  __syncthreads();
  const float* __restrict__ W = left ? Wl : Wr;
  float acc = 0.f;
#pragma unroll 8
  for (int c = 0; c < Cq; ++c) acc = fmaf(xs[c], W[c * Eq + e], acc);
  acc += left ? bl[e] : br[e];
  if (left) {
    __builtin_nontemporal_store(acc, &xl[(size_t)row * Eq + e]);
  } else {
    // plane-major: xrP[ch=e>>2][row][c=e&3]
    __builtin_nontemporal_store(acc, &xrP[((size_t)(e >> 2) * BN + row) * 4 + (e & 3)]);
    float s = acc * att[e];                 // rdot[row] = sum_e xr[row][e]*att[e]
    s += DPP_F(s, QP_XOR1);
    s += DPP_F(s, QP_XOR2);
    s += DPP_F(s, ROR4);
    s += DPP_F(s, ROR8);
    const float sd = (RL_F(s, 0) + RL_F(s, 16)) + (RL_F(s, 32) + RL_F(s, 48));
    if (e == 0) __builtin_nontemporal_store(sd, &rdot[row]);
  }
}

// ---------------- attn: R11-EXACT (best measured total). No changes. ----------------
// grid = BN/4 = 512 blocks, block = 512 (8 waves), plain __launch_bounds__(512).
__global__ __launch_bounds__(512) void attn_kernel(
    const float* __restrict__ xl, const float* __restrict__ xrP,
    const float* __restrict__ rdot, const float* __restrict__ att,
    float* __restrict__ out) {
  const int r0g  = blockIdx.x * TI;
  const int b    = r0g >> 10;
  const int tid  = threadIdx.x;
  const int lane = tid & 63;
  const int wave = tid >> 6;

  __shared__ float alpha[TI][Nq];   // 16 KB

  // ---- phase 1: V_C core (4 rows x 2 j, 1-ahead pipeline) ----
  {
    const int jt = tid;
    const float* __restrict__ xlw = xl + (size_t)r0g * Eq;  // block-uniform -> s_load

    const float rd0 = 1.5f * rdot[b * Nq + jt];
    const float rd1 = 1.5f * rdot[b * Nq + jt + 512];
    float acc[TI][2];
#pragma unroll
    for (int r = 0; r < TI; ++r) { acc[r][0] = rd0; acc[r][1] = rd1; }

    const float* __restrict__ vb = xrP + (size_t)(b * Nq + jt) * 4;
    // 1-ahead software pipeline (prefetch ch=0)
    float4 nv0 = *(const float4*)(vb);
    float4 nv1 = *(const float4*)(vb + 512 * 4);
    float4 na0 = *(const float4*)(xlw);
    float4 na1 = *(const float4*)(xlw + Eq);
    float4 na2 = *(const float4*)(xlw + 2 * Eq);
    float4 na3 = *(const float4*)(xlw + 3 * Eq);
    float4 nat = *(const float4*)(att);

#pragma unroll
    for (int ch = 0; ch < 16; ++ch) {
      const float4 v0 = nv0, v1 = nv1;
      const float4 a0 = na0, a1 = na1, a2 = na2, a3 = na3, at = nat;
      if (ch < 15) {                      // issue ch+1 loads before computing ch
        vb += BN * 4;                     // next plane
        nv0 = *(const float4*)(vb);
        nv1 = *(const float4*)(vb + 512 * 4);
        na0 = *(const float4*)(xlw + (ch + 1) * 4);
        na1 = *(const float4*)(xlw + Eq + (ch + 1) * 4);
        na2 = *(const float4*)(xlw + 2 * Eq + (ch + 1) * 4);
        na3 = *(const float4*)(xlw + 3 * Eq + (ch + 1) * 4);
        nat = *(const float4*)(att + (ch + 1) * 4);
      }
      const float* v0p = (const float*)&v0;
      const float* v1p = (const float*)&v1;
      const float* a0p = (const float*)&a0;
      const float* a1p = (const float*)&a1;
      const float* a2p = (const float*)&a2;
      const float* a3p = (const float*)&a3;
      const float* atp = (const float*)&at;
#pragma unroll
      for (int dd = 0; dd < 4; ++dd) {
        const float a = atp[dd];
        const float x0 = v0p[dd], x1 = v1p[dd];
        acc[0][0] = fmaf(fabsf(a0p[dd] + x0), a, acc[0][0]);
        acc[0][1] = fmaf(fabsf(a0p[dd] + x1), a, acc[0][1]);
        acc[1][0] = fmaf(fabsf(a1p[dd] + x0), a, acc[1][0]);
        acc[1][1] = fmaf(fabsf(a1p[dd] + x1), a, acc[1][1]);
        acc[2][0] = fmaf(fabsf(a2p[dd] + x0), a, acc[2][0]);
        acc[2][1] = fmaf(fabsf(a2p[dd] + x1), a, acc[2][1]);
        acc[3][0] = fmaf(fabsf(a3p[dd] + x0), a, acc[3][0]);
        acc[3][1] = fmaf(fabsf(a3p[dd] + x1), a, acc[3][1]);
      }
    }
#pragma unroll
    for (int r = 0; r < TI; ++r) {
      alpha[r][jt]       = acc[r][0];
      alpha[r][jt + 512] = acc[r][1];
    }
  }
  __syncthreads();

  // ---- phase 2: waves 0..3 = top-K of row `wave`, DPP-only reduces ----
  if (wave < TI) {
    float vals[16];
#pragma unroll
    for (int s = 0; s < 16; ++s) vals[s] = alpha[wave][lane + 64 * s];

    float lv = vals[0];
    int   pk = lane;                      // pk = (s<<6)|lane == j
#pragma unroll
    for (int s = 1; s < 16; ++s)
      if (vals[s] > lv) { lv = vals[s]; pk = (s << 6) | lane; }

    float m0 = 0.f, ssum = 0.f, myv = 0.f;
    int myi = 0;
#pragma unroll 1
    for (int round = 0; round < Kq; ++round) {
      float m = lv;
      m = fmaxf(m, DPP_F(m, QP_XOR1));
      m = fmaxf(m, DPP_F(m, QP_XOR2));
      m = fmaxf(m, DPP_F(m, ROR4));
      m = fmaxf(m, DPP_F(m, ROR8));
      const float bv = fmaxf(fmaxf(RL_F(m, 0), RL_F(m, 16)),
                             fmaxf(RL_F(m, 32), RL_F(m, 48)));
      int key = (lv == bv) ? pk : 0x7FFFFFFF;   // min-j tie-break (lax.top_k)
      key = min(key, DPP_I(key, QP_XOR1));
      key = min(key, DPP_I(key, QP_XOR2));
      key = min(key, DPP_I(key, ROR4));
      key = min(key, DPP_I(key, ROR8));
      const int jsel = min(min(RL_I(key, 0), RL_I(key, 16)),
                           min(RL_I(key, 32), RL_I(key, 48)));
      if (round == 0) m0 = bv;
      ssum += __expf(0.4f * (bv - m0));   // undo the /0.4 scaling here
      if (lane == round) { myv = bv; myi = jsel; }
      if (lane == (jsel & 63)) {          // owner knockout + rescan
        const int sk = jsel >> 6;
#pragma unroll
        for (int s = 0; s < 16; ++s)
          if (s == sk) vals[s] = NEGF;
        lv = vals[0]; pk = lane;
#pragma unroll
        for (int s = 1; s < 16; ++s)
          if (vals[s] > lv) { lv = vals[s]; pk = (s << 6) | lane; }
      }
    }

    if (lane < Kq) {
      const int gi = r0g + wave;
      const float p = __expf(0.4f * (myv - m0)) / ssum;
      const int base = gi * Kq + lane;
      out[base]            = (float)gi;              // index_i
      out[BNK + base]      = (float)(b * Nq + myi);  // index_j
      out[2 * BNK + base]  = p;                      // attention
    }
  }
}

extern "C" void kernel_launch(void* const* d_in, const int* in_sizes, int n_in,
                              void* d_out, int out_size, void* d_ws, size_t ws_size,
                              hipStream_t stream) {
  const float* x   = (const float*)d_in[0];
  const float* Wl  = (const float*)d_in[1];
  const float* bl  = (const float*)d_in[2];
  const float* Wr  = (const float*)d_in[3];
  const float* br  = (const float*)d_in[4];
  const float* att = (const float*)d_in[5];
  float* out = (float*)d_out;

  float* xl   = (float*)d_ws;                    // [B*N, E]
  float* xrP  = xl + (size_t)BN * Eq;            // [16][B*N][4] plane-major
  float* rdot = xrP + (size_t)16 * BN * 4;       // [B*N]

  proj_kernel<<<BN, 128, 0, stream>>>(x, Wl, bl, Wr, br, att, xl, xrP, rdot);
  attn_kernel<<<BN / TI, 512, 0, stream>>>(xl, xrP, rdot, att, out);
}